// Round 9
// baseline (33709.311 us; speedup 1.0000x reference)
//
#include <hip/hip_runtime.h>

// Persistent-LSTM MI355X — Round 15: R14 + data-first fast path.
// R14 (speculative slice read under the gate) validated: 32.2 -> 30.0ms,
// FETCH 1.0GB (harmless, 0.7% HBM). R15 removes the gate from the path of
// the wave that sets the period: the STRAGGLER. Its producers published
// long ago, so its speculative words validate immediately — yet R14 still
// burned a tag-gate round trip (~L-2L) on it. Now: check the speculative
// words' embedded tags FIRST; if all fresh, skip the gate entirely. On
// miss (early waves), fall into R14's 3-deep tag gate + validate verbatim.
// Traffic unchanged: the fast-path check reuses the already-issued spec
// loads; data lines still see exactly one read per consumer per step
// (no R7-style data polling). Correctness carried by word validation
// (R12's tag-chain argument); the gate is traffic-shaping only.
// Session laws (all respected):
//   (1) h written ONCE, pulled via LLC (R13: push = 134GB writes, death)
//   (2) producer publish: word stores -> __syncthreads drain -> tid0 tag
//       (R7/R8/R10/R12: every early/lockfree variant +1.5-2us/step)
//   (3) sleep-paced compact-tag gate for early waves (R7: data-poll storm)
//   (4) geometry 256x512 fixed, weights VGPR-resident (R9: VGPR cap)
//   (5) straggler-max amplifies per-wave latency savings 2-3x (R11, R14)
// 0xAA ws poison: negative signed tag -> stale/inert (R3-R14 validated).
// ws: hq u64[2][2048] (32KB) + slots u32[256] (1KB).

#define H      2048
#define TSTEPS 8192
#define FEAT   128
#define NBLK   256
#define NTHR   512

typedef float vf4 __attribute__((ext_vector_type(4)));
typedef float vf2 __attribute__((ext_vector_type(2)));
typedef unsigned long long u64;
typedef unsigned int u32;

__device__ __forceinline__ float sigm(float xv) {
  return __builtin_amdgcn_rcpf(1.0f + __expf(-xv));
}
__device__ __forceinline__ float tanh_(float xv) {
  return 1.0f - 2.0f * __builtin_amdgcn_rcpf(__expf(2.0f * xv) + 1.0f);
}

__device__ __forceinline__ u64 aload64(const u64* p) {
  return __hip_atomic_load(p, __ATOMIC_RELAXED, __HIP_MEMORY_SCOPE_AGENT);
}
__device__ __forceinline__ u32 aload32(const u32* p) {
  return __hip_atomic_load(p, __ATOMIC_RELAXED, __HIP_MEMORY_SCOPE_AGENT);
}
__device__ __forceinline__ void astoreu(u32* p, u32 v) {
  __hip_atomic_store(p, v, __ATOMIC_RELAXED, __HIP_MEMORY_SCOPE_AGENT);
}
__device__ __forceinline__ void astore64(u64* p, u64 v) {
  __hip_atomic_store(p, v, __ATOMIC_RELAXED, __HIP_MEMORY_SCOPE_AGENT);
}
__device__ __forceinline__ int  tag_of(u64 d) { return (int)(u32)(d >> 32); }
__device__ __forceinline__ float val_of(u64 d) { return __uint_as_float((u32)d); }
__device__ __forceinline__ u64  pack(int tag, float v) {
  return ((u64)(u32)tag << 32) | (u64)__float_as_uint(v);
}

#define DECLG(g) vf4 w##g##_0, w##g##_1, w##g##_2, w##g##_3, \
                     w##g##_4, w##g##_5, w##g##_6, w##g##_7; \
                 vf2 wih##g; float bias##g; float acc##g;

#define LOADG(g) { \
  const int row_ = (g) * H + j; \
  const float* wr_ = W_hh + (long)row_ * H; \
  w##g##_0 = *(const vf4*)(wr_ + 4*(ln      )); \
  w##g##_1 = *(const vf4*)(wr_ + 4*(ln +  64)); \
  w##g##_2 = *(const vf4*)(wr_ + 4*(ln + 128)); \
  w##g##_3 = *(const vf4*)(wr_ + 4*(ln + 192)); \
  w##g##_4 = *(const vf4*)(wr_ + 4*(ln + 256)); \
  w##g##_5 = *(const vf4*)(wr_ + 4*(ln + 320)); \
  w##g##_6 = *(const vf4*)(wr_ + 4*(ln + 384)); \
  w##g##_7 = *(const vf4*)(wr_ + 4*(ln + 448)); \
  wih##g  = *(const vf2*)(W_ih + (long)row_ * FEAT + 2*ln); \
  bias##g = b_ih[row_] + b_hh[row_]; }

// Opaque pin: weights become non-rematerializable (cannot re-sink into loop).
#define PIN(g) asm volatile("" : \
  "+v"(w##g##_0), "+v"(w##g##_1), "+v"(w##g##_2), "+v"(w##g##_3), \
  "+v"(w##g##_4), "+v"(w##g##_5), "+v"(w##g##_6), "+v"(w##g##_7), \
  "+v"(wih##g), "+v"(bias##g));

#define LDSREAD(k, ldsrow) \
  const vf4 hv##k = *(const vf4*)&(ldsrow)[4*(ln + 64*(k))];

#define FMA_G(g, c) \
  acc##g = __builtin_fmaf(w##g##_##c.x, h4_.x, acc##g); \
  acc##g = __builtin_fmaf(w##g##_##c.y, h4_.y, acc##g); \
  acc##g = __builtin_fmaf(w##g##_##c.z, h4_.z, acc##g); \
  acc##g = __builtin_fmaf(w##g##_##c.w, h4_.w, acc##g);

#define FMA_C(c) { const vf4 h4_ = hv##c; \
  FMA_G(0, c) FMA_G(1, c) FMA_G(2, c) FMA_G(3, c) }

#define REDUCE(g) { float a_ = acc##g; \
  a_ += __shfl_xor(a_, 1);  a_ += __shfl_xor(a_, 2);  a_ += __shfl_xor(a_, 4); \
  a_ += __shfl_xor(a_, 8);  a_ += __shfl_xor(a_, 16); a_ += __shfl_xor(a_, 32); \
  acc##g = a_ + bias##g; }

// Wave wv: (1) issue 4 speculative slice-word loads; (2) FAST PATH: if all
// embedded tags already >= tgt, skip the gate (straggler case — zero added
// latency); (3) else: 3-deep pipelined compact-tag gate over its 32
// producers, then validate/re-read stale words (bounded: gate-pass =>
// visible => first re-read fresh); (4) stage floats to LDS.
__device__ __forceinline__ void poll_and_stage(const u32* __restrict__ slots,
                                               const u64* __restrict__ hq_par,
                                               int tgt,
                                               float* __restrict__ ldsrow,
                                               int wv, int ln) {
  const int base = wv * 256 + 4 * ln;
  const u64* hp = hq_par + base;
  u64 d0 = aload64(hp + 0);          // speculative: in flight now
  u64 d1 = aload64(hp + 1);
  u64 d2 = aload64(hp + 2);
  u64 d3 = aload64(hp + 3);

  if (!__all((tag_of(d0) >= tgt) & (tag_of(d1) >= tgt) &
             (tag_of(d2) >= tgt) & (tag_of(d3) >= tgt))) {
    // slow path: compact-tag gate (3-deep pipelined, sleep-paced)
    const u32* sp = slots + wv * 32 + (ln & 31);
    const bool act = (ln < 32);
    int v0 = act ? (int)aload32(sp) : 0x7fffffff;
    int v1 = act ? (int)aload32(sp) : 0x7fffffff;
    int v2 = act ? (int)aload32(sp) : 0x7fffffff;
    while (!__all(v0 >= tgt)) {
      __builtin_amdgcn_s_sleep(1);
      v0 = v1;
      v1 = v2;
      v2 = (act && v1 < tgt) ? (int)aload32(sp) : v1;
    }
    // gate passed: all words visible; re-read whatever is still stale.
    while (!__all((tag_of(d0) >= tgt) & (tag_of(d1) >= tgt) &
                  (tag_of(d2) >= tgt) & (tag_of(d3) >= tgt))) {
      if (tag_of(d0) < tgt) d0 = aload64(hp + 0);
      if (tag_of(d1) < tgt) d1 = aload64(hp + 1);
      if (tag_of(d2) < tgt) d2 = aload64(hp + 2);
      if (tag_of(d3) < tgt) d3 = aload64(hp + 3);
    }
  }
  vf4 hv;
  hv.x = val_of(d0);
  hv.y = val_of(d1);
  hv.z = val_of(d2);
  hv.w = val_of(d3);
  *(vf4*)&ldsrow[base] = hv;
}

__global__ __launch_bounds__(NTHR, 2)
void lstm_persist(const float* __restrict__ x,
                  const float* __restrict__ W_ih,
                  const float* __restrict__ W_hh,
                  const float* __restrict__ b_ih,
                  const float* __restrict__ b_hh,
                  const float* __restrict__ W_lin,
                  const float* __restrict__ b_lin,
                  const float* __restrict__ W_out,
                  const float* __restrict__ b_out,
                  float* __restrict__ out,
                  float* __restrict__ ws)
{
  const int tid = threadIdx.x;
  const int b   = blockIdx.x;
  const int wv  = tid >> 6;
  const int ln  = tid & 63;

  // ws: u64 hq[2][H] tagged h words (32KB); parity p serves steps t&1==p;
  // hq[1] reused for ylin (tag TSTEPS+1). slots: u32[256] compact tags.
  u64* hq    = (u64*)ws;
  u32* slots = (u32*)(ws + 4 * H);

  __shared__ __align__(16) float h_lds[2][H];

  // h_0 = 0: zero parity-0 LDS row (512 threads x 16B)
  *(vf4*)&h_lds[0][4 * tid] = (vf4)(0.0f);

  // ---- persistent weights: load then pin ----
  const int j = b * 8 + wv;
  DECLG(0) DECLG(1) DECLG(2) DECLG(3)
  LOADG(0) LOADG(1) LOADG(2) LOADG(3)
  PIN(0) PIN(1) PIN(2) PIN(3)

  __syncthreads();

  float cst = 0.0f;

  #pragma unroll 1
  for (int t = 0; t < TSTEPS; ++t) {
    const vf2 xr = *(const vf2*)(x + (long)t * FEAT + 2 * ln);
    float* ldsrow = h_lds[t & 1];

    if (t > 0)
      poll_and_stage(slots, hq + (t & 1) * H, t, ldsrow, wv, ln);
    __syncthreads();   // barrier #1: all slices staged before any LDS read

    LDSREAD(0, ldsrow) LDSREAD(1, ldsrow) LDSREAD(2, ldsrow) LDSREAD(3, ldsrow)
    LDSREAD(4, ldsrow) LDSREAD(5, ldsrow) LDSREAD(6, ldsrow) LDSREAD(7, ldsrow)

    acc0 = wih0.x * xr.x + wih0.y * xr.y;
    acc1 = wih1.x * xr.x + wih1.y * xr.y;
    acc2 = wih2.x * xr.x + wih2.y * xr.y;
    acc3 = wih3.x * xr.x + wih3.y * xr.y;

    FMA_C(0) FMA_C(1) FMA_C(2) FMA_C(3)
    FMA_C(4) FMA_C(5) FMA_C(6) FMA_C(7)

    REDUCE(0) REDUCE(1) REDUCE(2) REDUCE(3)

    // gate order [i, f, g, o]
    const float iv = sigm(acc0);
    const float fv = sigm(acc1);
    const float gv = tanh_(acc2);
    const float ov = sigm(acc3);
    cst = fv * cst + iv * gv;
    const float hval = ov * tanh_(cst);

    // publish h_{t+1} (R6-validated ordering, u64 self-validating word):
    // word store -> __syncthreads (drains vmcnt per wave) -> tid0 tag.
    if (ln == 0)
      astore64(hq + ((t + 1) & 1) * H + j, pack(t + 1, hval));
    __syncthreads();   // barrier #2: all 8 words visible before tag below
    if (tid == 0)
      astoreu(slots + b, (u32)(t + 1));
  }

  // ---- head phase 1: ylin[j] = b_lin[j] + dot(W_lin[j,:], h_final) ----
  // h_final words: parity 0, tag TSTEPS. Passing the gate/validation for
  // tag TSTEPS implies every block finished its step-8191 parity-1 reads ->
  // ylin store into hq[1] is WAR-safe.
  {
    float* ldsrow = h_lds[0];
    poll_and_stage(slots, hq, TSTEPS, ldsrow, wv, ln);
    __syncthreads();

    float a0 = 0.0f;
    const float* wl = W_lin + (long)j * H;
    #pragma unroll
    for (int k = 0; k < 8; ++k) {
      const vf4 h4 = *(const vf4*)&ldsrow[4 * (ln + 64 * k)];
      const vf4 u  = *(const vf4*)(wl + 4 * (ln + 64 * k));
      a0 += u.x * h4.x + u.y * h4.y + u.z * h4.z + u.w * h4.w;
    }
    a0 += __shfl_xor(a0, 1);  a0 += __shfl_xor(a0, 2);  a0 += __shfl_xor(a0, 4);
    a0 += __shfl_xor(a0, 8);  a0 += __shfl_xor(a0, 16); a0 += __shfl_xor(a0, 32);

    if (ln == 0)
      astore64(hq + H + j, pack(TSTEPS + 1, a0 + b_lin[j]));  // ylin word
    __syncthreads();   // drains vmcnt -> ylin visible before tag below
    if (tid == 0)
      astoreu(slots + b, (u32)(TSTEPS + 1));
  }

  // ---- head phase 2: y = ylin @ W_out.T + b_out (block 0, wave 0) ----
  // Barrier-ordered slot protocol; reads issued after gate (fresh).
  if (b == 0 && wv == 0) {
    const u32* sp = slots + 4 * ln;
    int v0 = (int)aload32(sp + 0), v1 = (int)aload32(sp + 1);
    int v2 = (int)aload32(sp + 2), v3 = (int)aload32(sp + 3);
    const int tgt = TSTEPS + 1;
    while (!__all((v0 >= tgt) & (v1 >= tgt) & (v2 >= tgt) & (v3 >= tgt))) {
      __builtin_amdgcn_s_sleep(1);
      if (v0 < tgt) v0 = (int)aload32(sp + 0);
      if (v1 < tgt) v1 = (int)aload32(sp + 1);
      if (v2 < tgt) v2 = (int)aload32(sp + 2);
      if (v3 < tgt) v3 = (int)aload32(sp + 3);
    }
    float p0 = 0.0f, p1 = 0.0f;
    #pragma unroll
    for (int k = 0; k < 32; ++k) {
      const u64 d  = aload64(hq + H + ln + 64 * k);
      const float y = val_of(d);
      const int c  = ln + 64 * k;
      p0 = __builtin_fmaf(W_out[c],     y, p0);
      p1 = __builtin_fmaf(W_out[H + c], y, p1);
    }
    p0 += __shfl_xor(p0, 1);  p0 += __shfl_xor(p0, 2);  p0 += __shfl_xor(p0, 4);
    p0 += __shfl_xor(p0, 8);  p0 += __shfl_xor(p0, 16); p0 += __shfl_xor(p0, 32);
    p1 += __shfl_xor(p1, 1);  p1 += __shfl_xor(p1, 2);  p1 += __shfl_xor(p1, 4);
    p1 += __shfl_xor(p1, 8);  p1 += __shfl_xor(p1, 16); p1 += __shfl_xor(p1, 32);
    if (ln == 0) {
      out[0] = p0 + b_out[0];
      out[1] = p1 + b_out[1];
    }
  }
}

extern "C" void kernel_launch(void* const* d_in, const int* in_sizes, int n_in,
                              void* d_out, int out_size, void* d_ws, size_t ws_size,
                              hipStream_t stream) {
  const float* x     = (const float*)d_in[0];
  const float* W_ih  = (const float*)d_in[1];
  const float* W_hh  = (const float*)d_in[2];
  const float* b_ih  = (const float*)d_in[3];
  const float* b_hh  = (const float*)d_in[4];
  const float* W_lin = (const float*)d_in[5];
  const float* b_lin = (const float*)d_in[6];
  const float* W_out = (const float*)d_in[7];
  const float* b_out = (const float*)d_in[8];

  lstm_persist<<<dim3(NBLK), dim3(NTHR), 0, stream>>>(
      x, W_ih, W_hh, b_ih, b_hh, W_lin, b_lin, W_out, b_out,
      (float*)d_out, (float*)d_ws);
}